// Round 1
// baseline (2426.411 us; speedup 1.0000x reference)
//
#include <hip/hip_runtime.h>
#include <cmath>

#define TT    2048
#define HH    128
#define G4    512      // 4*H gate rows
#define NDIN  3
#define NDOUT 26
#define NTHR  512

typedef _Float16 h2t __attribute__((ext_vector_type(2)));
typedef _Float16 h8t __attribute__((ext_vector_type(8)));

__device__ __forceinline__ float fdot2(h2t a, h2t b, float c) {
    return __builtin_amdgcn_fdot2(a, b, c, false);   // v_dot2_f32_f16
}

union H8u { h8t v; h2t h[4]; };

__device__ __forceinline__ float fast_rcp(float x) { return __builtin_amdgcn_rcpf(x); }

__global__ __launch_bounds__(NTHR, 2) void slstm2_kernel(
    const float* __restrict__ x,
    const float* __restrict__ W0, const float* __restrict__ R0, const float* __restrict__ b0,
    const float* __restrict__ W1, const float* __restrict__ R1, const float* __restrict__ b1,
    const float* __restrict__ Wmu, const float* __restrict__ bmu,
    const float* __restrict__ Wsig, const float* __restrict__ bsig,
    float* __restrict__ out, int B)
{
    const int b = blockIdx.x;
    const int j = threadIdx.x;   // gate row 0..511

    __shared__ float xs[TT * NDIN];                  // 24 KB staged input slice
    __shared__ __align__(16) _Float16 h1h[HH];       // layer1 hidden (f16 broadcast buf)
    __shared__ __align__(16) _Float16 h2h[HH];       // layer2 hidden
    __shared__ float g1[G4];                         // layer1 gate preacts
    __shared__ float g2[G4];                         // layer2 gate preacts
    __shared__ float h2f[HH];                        // final h2 in f32

    // ---- stage x[b] into LDS (coalesced) ----
    const float* xb = x + (size_t)b * (TT * NDIN);
    #pragma unroll
    for (int r = 0; r < (TT * NDIN) / NTHR; ++r)
        xs[r * NTHR + j] = xb[r * NTHR + j];

    // ---- load this thread's weight rows into registers as f16 pairs ----
    h2t wr0[64], ww1[64], wr1[64];   // 192 VGPRs of weights
    {
        const float4* r0p = (const float4*)(R0 + (size_t)j * HH);
        const float4* w1p = (const float4*)(W1 + (size_t)j * HH);
        const float4* r1p = (const float4*)(R1 + (size_t)j * HH);
        #pragma unroll
        for (int k = 0; k < 32; ++k) {
            float4 a = r0p[k];
            h2t t0 = {(_Float16)a.x, (_Float16)a.y};
            h2t t1 = {(_Float16)a.z, (_Float16)a.w};
            wr0[2*k] = t0; wr0[2*k+1] = t1;
            float4 c = w1p[k];
            h2t t2 = {(_Float16)c.x, (_Float16)c.y};
            h2t t3 = {(_Float16)c.z, (_Float16)c.w};
            ww1[2*k] = t2; ww1[2*k+1] = t3;
            float4 d = r1p[k];
            h2t t4 = {(_Float16)d.x, (_Float16)d.y};
            h2t t5 = {(_Float16)d.z, (_Float16)d.w};
            wr1[2*k] = t4; wr1[2*k+1] = t5;
        }
    }
    const float w0a = W0[j*NDIN+0], w0b = W0[j*NDIN+1], w0c = W0[j*NDIN+2];
    const float b0j = b0[j], b1j = b1[j];

    if (j < HH) { h1h[j] = (_Float16)0.f; h2h[j] = (_Float16)0.f; }
    // per-element sLSTM state: threads 0..127 own layer1 element j,
    // threads 128..255 own layer2 element j-128
    float c_s = 0.f, n_s = 0.f, m_s = 0.f, hlast = 0.f;

    __syncthreads();

    const h8t* h1p = (const h8t*)h1h;
    const h8t* h2p = (const h8t*)h2h;

    // Pipelined loop: iteration t computes layer1 preacts for step t
    // and layer2 preacts for step t-1 (both consume h1[t-1]; layer2's
    // recurrent term consumes h2[t-2], still in h2h). Update phase then
    // advances layer1 to h1[t] (waves 0-1) and layer2 to h2[t-1] (waves 2-3).
    for (int t = 0; t <= TT; ++t) {
        const int tc = (t < TT) ? t : (TT - 1);
        const float xv0 = xs[tc*3+0], xv1 = xs[tc*3+1], xv2 = xs[tc*3+2];

        float a0=0.f,a1=0.f,a2=0.f,a3=0.f;   // R0 . h1[t-1]
        float d0=0.f,d1=0.f,d2=0.f,d3=0.f;   // W1 . h1[t-1]
        float e0=0.f,e1=0.f,e2=0.f,e3=0.f;   // R1 . h2[t-2]
        #pragma unroll
        for (int kk = 0; kk < 16; ++kk) {
            H8u u1, u2;
            u1.v = h1p[kk];   // 16B LDS broadcast read
            u2.v = h2p[kk];
            a0 = fdot2(wr0[4*kk+0], u1.h[0], a0);
            a1 = fdot2(wr0[4*kk+1], u1.h[1], a1);
            a2 = fdot2(wr0[4*kk+2], u1.h[2], a2);
            a3 = fdot2(wr0[4*kk+3], u1.h[3], a3);
            d0 = fdot2(ww1[4*kk+0], u1.h[0], d0);
            d1 = fdot2(ww1[4*kk+1], u1.h[1], d1);
            d2 = fdot2(ww1[4*kk+2], u1.h[2], d2);
            d3 = fdot2(ww1[4*kk+3], u1.h[3], d3);
            e0 = fdot2(wr1[4*kk+0], u2.h[0], e0);
            e1 = fdot2(wr1[4*kk+1], u2.h[1], e1);
            e2 = fdot2(wr1[4*kk+2], u2.h[2], e2);
            e3 = fdot2(wr1[4*kk+3], u2.h[3], e3);
        }
        g1[j] = b0j + w0a*xv0 + w0b*xv1 + w0c*xv2 + ((a0+a1)+(a2+a3));
        g2[j] = b1j + ((d0+d1)+(d2+d3)) + ((e0+e1)+(e2+e3));
        __syncthreads();

        if (t < TT && j < HH) {
            // layer1 state update for step t (waves 0-1)
            const float it = g1[j], ft = g1[HH+j], zt = g1[2*HH+j], ot = g1[3*HH+j];
            const float mn = fmaxf(ft + m_s, it);
            const float iv = __expf(it - mn);
            const float fv = __expf(ft + m_s - mn);
            const float tq = __expf(-2.f * fabsf(zt));
            float zv = (1.f - tq) * fast_rcp(1.f + tq);
            zv = (zt < 0.f) ? -zv : zv;
            const float ov = fast_rcp(1.f + __expf(-ot));
            c_s = fv * c_s + iv * zv;
            n_s = fv * n_s + iv;
            m_s = mn;
            const float hv = ov * (c_s * fast_rcp(n_s));
            h1h[j] = (_Float16)hv;
        } else if (t > 0 && j >= HH && j < 2*HH) {
            // layer2 state update for step t-1 (waves 2-3)
            const int e = j - HH;
            const float it = g2[e], ft = g2[HH+e], zt = g2[2*HH+e], ot = g2[3*HH+e];
            const float mn = fmaxf(ft + m_s, it);
            const float iv = __expf(it - mn);
            const float fv = __expf(ft + m_s - mn);
            const float tq = __expf(-2.f * fabsf(zt));
            float zv = (1.f - tq) * fast_rcp(1.f + tq);
            zv = (zt < 0.f) ? -zv : zv;
            const float ov = fast_rcp(1.f + __expf(-ot));
            c_s = fv * c_s + iv * zv;
            n_s = fv * n_s + iv;
            m_s = mn;
            const float hv = ov * (c_s * fast_rcp(n_s));
            hlast = hv;
            h2h[e] = (_Float16)hv;
        }
        __syncthreads();
    }

    // ---- output heads: last = h2[:, T-1, :] in f32 ----
    if (j >= HH && j < 2*HH) h2f[j - HH] = hlast;
    __syncthreads();

    if (j < 2 * NDOUT) {
        const int d = (j < NDOUT) ? j : (j - NDOUT);
        const float* Wr = ((j < NDOUT) ? Wmu : Wsig) + (size_t)d * HH;
        float acc = (j < NDOUT) ? bmu[d] : bsig[d];
        #pragma unroll 8
        for (int k = 0; k < HH; ++k) acc += h2f[k] * Wr[k];
        if (j < NDOUT) {
            out[(size_t)b * NDOUT + d] = acc;
        } else {
            const float sp = fmaxf(acc, 0.f) + log1pf(__expf(-fabsf(acc)));
            out[(size_t)B * NDOUT + (size_t)b * NDOUT + d] = sp + 1e-6f;
        }
    }
}

extern "C" void kernel_launch(void* const* d_in, const int* in_sizes, int n_in,
                              void* d_out, int out_size, void* d_ws, size_t ws_size,
                              hipStream_t stream) {
    const float* x    = (const float*)d_in[0];
    const float* W0   = (const float*)d_in[1];
    const float* R0   = (const float*)d_in[2];
    const float* b0   = (const float*)d_in[3];
    const float* W1   = (const float*)d_in[4];
    const float* R1   = (const float*)d_in[5];
    const float* b1   = (const float*)d_in[6];
    const float* Wmu  = (const float*)d_in[7];
    const float* bmu  = (const float*)d_in[8];
    const float* Wsig = (const float*)d_in[9];
    const float* bsig = (const float*)d_in[10];
    float* out = (float*)d_out;

    const int B = in_sizes[0] / (TT * NDIN);   // 256

    slstm2_kernel<<<B, NTHR, 0, stream>>>(x, W0, R0, b0, W1, R1, b1,
                                          Wmu, bmu, Wsig, bsig, out, B);
}